// Round 4
// baseline (387.597 us; speedup 1.0000x reference)
//
#include <hip/hip_runtime.h>
#include <cstdint>

// Problem constants: L=S=1024, N=4, E=1024, H=16, D=64
typedef __bf16 bf16x8 __attribute__((ext_vector_type(8)));
typedef float f32x4 __attribute__((ext_vector_type(4)));

// ws layout (float-unit offsets):
static const size_t OFF_QW2BF = 0;         // [k*64+i][j] bf16 (1M ushort)
static const size_t OFF_KWBF  = 524288;    // [o][j] bf16
static const size_t OFF_VWBF  = 1048576;   // [o][j] bf16
static const size_t OFF_OWTBF = 1572864;   // [o][j] bf16 (out_w^T)
static const size_t OFF_QB2   = 2097152;   // 1024 f32
static const size_t OFF_QWBF  = 2098176;   // [n][k][l][i] bf16 (4M ushort)
static const size_t OFF_KHBF  = 4195328;   // [n][k][s][i] bf16
static const size_t OFF_VTBF  = 6292480;   // [n][k][i][s] bf16 (V^T per head)
static const size_t OFF_ST    = 8389632;   // [n][k][l][{m,Z}] f32 131072
static const size_t OFF_OBF   = 8520704;   // [l*4+n][e] bf16 (4M ushort)

__device__ inline unsigned short f2bf(float f) {
  union { float f; unsigned u; } v; v.f = f;
  const unsigned r = v.u + 0x7FFFu + ((v.u >> 16) & 1u);   // RNE
  return (unsigned short)(r >> 16);
}

// ---------------------------------------------------------------------------
// K0: fold attn_W into q_w (bf16 out): qw2[(k,i),j] = sum_o q_w[o*16+k,j]*attn_W[o,i,k]/32
__global__ __launch_bounds__(256) void k_qw2(const float* __restrict__ qw,
    const float* __restrict__ attnW, const float* __restrict__ bias0,
    unsigned short* __restrict__ qw2, float* __restrict__ qb2) {
  const int b = blockIdx.x;          // = k*64 + i
  const int k = b >> 6, i = b & 63;
  const int tid = threadIdx.x;
  __shared__ float aw[64];
  if (tid < 64) aw[tid] = attnW[(tid * 64 + i) * 16 + k] * 0.03125f; // fold 1/sqrt(E)
  __syncthreads();
  for (int j = tid; j < 1024; j += 256) {
    float acc = 0.f;
#pragma unroll 8
    for (int o = 0; o < 64; ++o) acc = fmaf(qw[(o * 16 + k) * 1024 + j], aw[o], acc);
    qw2[(size_t)b * 1024 + j] = f2bf(acc);
  }
  if (tid == 0) {
    float acc = 0.f;
    for (int o = 0; o < 64; ++o) acc = fmaf(bias0[o * 16 + k], aw[o], acc);
    qb2[b] = acc;
  }
}

// ---------------------------------------------------------------------------
// Convert k_w and v_w to bf16 (row layout preserved: [o][j])
__global__ __launch_bounds__(256) void k_cvt2(const float* __restrict__ a,
    const float* __restrict__ b, unsigned short* __restrict__ oa,
    unsigned short* __restrict__ ob) {
  const int i = blockIdx.x * 256 + threadIdx.x;
  const float4 va = ((const float4*)a)[i];
  ushort4 ha; ha.x = f2bf(va.x); ha.y = f2bf(va.y); ha.z = f2bf(va.z); ha.w = f2bf(va.w);
  ((ushort4*)oa)[i] = ha;
  const float4 vb = ((const float4*)b)[i];
  ushort4 hb; hb.x = f2bf(vb.x); hb.y = f2bf(vb.y); hb.z = f2bf(vb.z); hb.w = f2bf(vb.w);
  ((ushort4*)ob)[i] = hb;
}

// ---------------------------------------------------------------------------
// Transpose out_w [j][o] -> owT [o][j] bf16
__global__ __launch_bounds__(256) void k_tr(const float* __restrict__ w,
    unsigned short* __restrict__ wt) {
  __shared__ float t[64][65];
  const int j0 = blockIdx.y * 64, o0 = blockIdx.x * 64;
  const int tid = threadIdx.x;
  const int r = tid >> 4, c4 = tid & 15;
#pragma unroll
  for (int q = 0; q < 4; ++q) {
    const int row = r + q * 16;
    const float4 v = *(const float4*)&w[(size_t)(j0 + row) * 1024 + o0 + c4 * 4];
    t[row][c4 * 4 + 0] = v.x; t[row][c4 * 4 + 1] = v.y;
    t[row][c4 * 4 + 2] = v.z; t[row][c4 * 4 + 3] = v.w;
  }
  __syncthreads();
#pragma unroll
  for (int q = 0; q < 4; ++q) {
    const int orow = r + q * 16;
    ushort4 h;
    h.x = f2bf(t[c4 * 4 + 0][orow]); h.y = f2bf(t[c4 * 4 + 1][orow]);
    h.z = f2bf(t[c4 * 4 + 2][orow]); h.w = f2bf(t[c4 * 4 + 3][orow]);
    *(ushort4*)&wt[(size_t)(o0 + orow) * 1024 + j0 + c4 * 4] = h;
  }
}

// ---------------------------------------------------------------------------
// bf16 MFMA GEMM: C[m,o] = sum_j A[m,j]*B[o,j] + bias[o].  M=4096,O=1024,K=1024.
// MODE 0: A fp32 (Q), epilogue bf16 scatter -> Qw[n][k][l][i] (o = k*64+i)
// MODE 1: A fp32 (K), epilogue bf16 scatter -> Kh[n][k][s][i] (o = i*16+k)
// MODE 3: A fp32 (V), epilogue bf16 scatter -> Vt[n][k][i][s] (o = i*16+k)
// MODE 2: A bf16 (Obf), epilogue f32 direct C[m*1024+o]
template <int MODE>
__global__ __launch_bounds__(256) void k_gemm(const void* __restrict__ Ap,
    const unsigned short* __restrict__ Bbf, const float* __restrict__ bias,
    void* __restrict__ C) {
  __shared__ unsigned short As[128][40];
  __shared__ unsigned short Bs[128][40];
  const int tid = threadIdx.x;
  const int wid = tid >> 6, lane = tid & 63;
  const int wr = wid >> 1, wc = wid & 1;
  const int lr = lane & 15, lk = lane >> 4;
  const int m0 = blockIdx.y * 128, o0 = blockIdx.x * 128;
  f32x4 acc[4][4];
#pragma unroll
  for (int i = 0; i < 4; ++i)
#pragma unroll
    for (int j = 0; j < 4; ++j) acc[i][j] = (f32x4){0.f, 0.f, 0.f, 0.f};

  for (int k0 = 0; k0 < 1024; k0 += 32) {
    if (MODE == 2) {
      const unsigned short* A = (const unsigned short*)Ap;
#pragma unroll
      for (int q = 0; q < 2; ++q) {
        const int idx = tid + q * 256;
        const int row = idx >> 2, c8 = idx & 3;
        *(int4*)&As[row][c8 * 8] =
            *(const int4*)&A[(size_t)(m0 + row) * 1024 + k0 + c8 * 8];
      }
    } else {
      const float* A = (const float*)Ap;
#pragma unroll
      for (int q = 0; q < 4; ++q) {
        const int idx = tid + q * 256;
        const int row = idx >> 3, c4 = idx & 7;
        const float4 v = *(const float4*)&A[(size_t)(m0 + row) * 1024 + k0 + c4 * 4];
        ushort4 h; h.x = f2bf(v.x); h.y = f2bf(v.y); h.z = f2bf(v.z); h.w = f2bf(v.w);
        *(ushort4*)&As[row][c4 * 4] = h;
      }
    }
#pragma unroll
    for (int q = 0; q < 2; ++q) {
      const int idx = tid + q * 256;
      const int row = idx >> 2, c8 = idx & 3;
      *(int4*)&Bs[row][c8 * 8] =
          *(const int4*)&Bbf[(size_t)(o0 + row) * 1024 + k0 + c8 * 8];
    }
    __syncthreads();
    bf16x8 af[4], bfr[4];
#pragma unroll
    for (int f = 0; f < 4; ++f)
      af[f] = *(const bf16x8*)&As[wr * 64 + f * 16 + lr][lk * 8];
#pragma unroll
    for (int f = 0; f < 4; ++f)
      bfr[f] = *(const bf16x8*)&Bs[wc * 64 + f * 16 + lr][lk * 8];
#pragma unroll
    for (int i = 0; i < 4; ++i)
#pragma unroll
      for (int j = 0; j < 4; ++j)
        acc[i][j] = __builtin_amdgcn_mfma_f32_16x16x32_bf16(af[i], bfr[j], acc[i][j], 0, 0, 0);
    __syncthreads();
  }
#pragma unroll
  for (int fi = 0; fi < 4; ++fi)
#pragma unroll
    for (int fj = 0; fj < 4; ++fj) {
      const int o = o0 + wc * 64 + fj * 16 + lr;
      const float bo = bias[o];
#pragma unroll
      for (int t = 0; t < 4; ++t) {
        const int m = m0 + wr * 64 + fi * 16 + lk * 4 + t;
        const float v = acc[fi][fj][t] + bo;
        if (MODE == 0) {
          const int kk = o >> 6, ii = o & 63, l = m >> 2, nn = m & 3;
          ((unsigned short*)C)[(((size_t)(nn * 16 + kk) * 1024 + l) << 6) + ii] = f2bf(v);
        } else if (MODE == 1) {
          const int kk = o & 15, ii = o >> 4, s = m >> 2, nn = m & 3;
          ((unsigned short*)C)[(((size_t)(nn * 16 + kk) * 1024 + s) << 6) + ii] = f2bf(v);
        } else if (MODE == 3) {
          const int kk = o & 15, ii = o >> 4, s = m >> 2, nn = m & 3;
          ((unsigned short*)C)[(((size_t)(nn * 16 + kk) * 64 + ii) << 10) + s] = f2bf(v);
        } else {
          ((float*)C)[(size_t)m * 1024 + o] = v;
        }
      }
    }
}

// ---------------------------------------------------------------------------
// MFMA flash v3: barrier-free. Per (n,k,l-tile=64); 4 waves x 16 q-rows.
// K/V fragments read directly from global (L2-resident, 3MB/XCD with swizzle).
// Swapped QK (A=K, B=Q): lane owns full score row for q=lane&15 -> in-register
// max/sum + 2 shfls. P packed to wave-private swizzled LDS (4x b64), read back
// as PV A-frags (2x b128). No __syncthreads anywhere.
__global__ __launch_bounds__(256) void k_flash(
    const unsigned short* __restrict__ Qbf, const unsigned short* __restrict__ Khbf,
    const unsigned short* __restrict__ Vtbf, float* __restrict__ stats,
    unsigned short* __restrict__ Obf) {
  __shared__ unsigned short Ps[64 * 64];   // [q][s] bf16, 8B-chunk XOR swizzle
  const int ob = blockIdx.x;
  const int b = (ob & 7) * 128 + (ob >> 3);   // bijective XCD swizzle
  const int lt = b & 15, k = (b >> 4) & 15, n = b >> 8;
  const int l0 = lt * 64;
  const int tid = threadIdx.x, w = tid >> 6, lane = tid & 63;
  const int lr = lane & 15, lk = lane >> 4;
  const size_t hb = (size_t)(n * 16 + k) * 65536;
  // Q fragments (B-operand): row = lr, k-chunks lk*8 / 32+lk*8
  const unsigned short* qrow = Qbf + hb + (size_t)(l0 + w * 16 + lr) * 64;
  const bf16x8 qa0 = *(const bf16x8*)(qrow + lk * 8);
  const bf16x8 qa1 = *(const bf16x8*)(qrow + 32 + lk * 8);
  const unsigned short* Kb = Khbf + hb;
  const unsigned short* Vb = Vtbf + hb;
  const int qloc = w * 16 + lr;           // this lane's score-row (QK col layout)
  const int swz = qloc & 7;

  float m_ = -1e30f, Z_ = 0.f;            // per-lane: stats of q-row qloc
  f32x4 oacc[4];
#pragma unroll
  for (int it = 0; it < 4; ++it) oacc[it] = (f32x4){0.f, 0.f, 0.f, 0.f};

  for (int s0 = 0; s0 < 1024; s0 += 64) {
    // K fragments (A-operand): rows s = s0+st*16+lr, k-chunks lk*8 / 32+lk*8
    bf16x8 kf0[4], kf1[4];
#pragma unroll
    for (int st = 0; st < 4; ++st) {
      const unsigned short* kr = Kb + (size_t)(s0 + st * 16 + lr) * 64;
      kf0[st] = *(const bf16x8*)(kr + lk * 8);
      kf1[st] = *(const bf16x8*)(kr + 32 + lk * 8);
    }
    // V fragments (B-operand for PV): rows i = it*16+lr, k(s)-chunks lk*8 / 32+lk*8
    bf16x8 vf0[4], vf1[4];
#pragma unroll
    for (int it = 0; it < 4; ++it) {
      const unsigned short* vr = Vb + (size_t)(it * 16 + lr) * 1024 + s0;
      vf0[it] = *(const bf16x8*)(vr + lk * 8);
      vf1[it] = *(const bf16x8*)(vr + 32 + lk * 8);
    }
    // swapped QK^T: C[col=q=lr][row = s_loc = st*16 + lk*4 + t]
    f32x4 sc[4];
#pragma unroll
    for (int st = 0; st < 4; ++st) {
      f32x4 z = (f32x4){0.f, 0.f, 0.f, 0.f};
      z = __builtin_amdgcn_mfma_f32_16x16x32_bf16(kf0[st], qa0, z, 0, 0, 0);
      sc[st] = __builtin_amdgcn_mfma_f32_16x16x32_bf16(kf1[st], qa1, z, 0, 0, 0);
    }
    // online softmax: lane holds 16 score entries of row qloc
    float tm = fmaxf(fmaxf(fmaxf(sc[0][0], sc[0][1]), fmaxf(sc[0][2], sc[0][3])),
                     fmaxf(fmaxf(sc[1][0], sc[1][1]), fmaxf(sc[1][2], sc[1][3])));
    tm = fmaxf(tm, fmaxf(fmaxf(fmaxf(sc[2][0], sc[2][1]), fmaxf(sc[2][2], sc[2][3])),
                         fmaxf(fmaxf(sc[3][0], sc[3][1]), fmaxf(sc[3][2], sc[3][3]))));
    tm = fmaxf(tm, __shfl_xor(tm, 16));
    tm = fmaxf(tm, __shfl_xor(tm, 32));
    const float mn = fmaxf(m_, tm);
    const float fac = __expf(m_ - mn);
    m_ = mn;
    float rs = 0.f;
    float p[4][4];
#pragma unroll
    for (int st = 0; st < 4; ++st)
#pragma unroll
      for (int t = 0; t < 4; ++t) {
        p[st][t] = __expf(sc[st][t] - mn);
        rs += p[st][t];
      }
    rs += __shfl_xor(rs, 16);
    rs += __shfl_xor(rs, 32);
    Z_ = Z_ * fac + rs;
    // P write: 4 packed b64 (s = st*16+lk*4..+3 consecutive), swizzled 8B chunks
#pragma unroll
    for (int st = 0; st < 4; ++st) {
      ushort4 pk;
      pk.x = f2bf(p[st][0]); pk.y = f2bf(p[st][1]);
      pk.z = f2bf(p[st][2]); pk.w = f2bf(p[st][3]);
      const int c = (st * 4 + lk) ^ (swz << 1);
      *(ushort4*)&Ps[qloc * 64 + c * 4] = pk;
    }
    // redistribute fac to PV row layout (rows q = lk*4+t)
    float fr[4];
#pragma unroll
    for (int t = 0; t < 4; ++t) fr[t] = __shfl(fac, lk * 4 + t);
    const f32x4 facv = {fr[0], fr[1], fr[2], fr[3]};
    // P A-frags: row = qloc, 16B chunk j' = j ^ swz
    const bf16x8 pa0 = *(const bf16x8*)&Ps[qloc * 64 + ((lk ^ swz) << 3)];
    const bf16x8 pa1 = *(const bf16x8*)&Ps[qloc * 64 + (((4 + lk) ^ swz) << 3)];
    // PV: C[col=i=it*16+lr][row = q = lk*4+t]
#pragma unroll
    for (int it = 0; it < 4; ++it) {
      f32x4 o = oacc[it] * facv;
      o = __builtin_amdgcn_mfma_f32_16x16x32_bf16(pa0, vf0[it], o, 0, 0, 0);
      oacc[it] = __builtin_amdgcn_mfma_f32_16x16x32_bf16(pa1, vf1[it], o, 0, 0, 0);
    }
  }
  if (lane < 16) {
    const size_t so = ((size_t)(n * 16 + k) * 1024 + l0 + w * 16 + lr) * 2;
    stats[so] = m_;
    stats[so + 1] = Z_;
  }
  const float iz = 1.f / Z_;
  float izr[4];
#pragma unroll
  for (int t = 0; t < 4; ++t) izr[t] = __shfl(iz, lk * 4 + t);
#pragma unroll
  for (int it = 0; it < 4; ++it)
#pragma unroll
    for (int t = 0; t < 4; ++t) {
      const int l = l0 + w * 16 + lk * 4 + t;
      const int i = it * 16 + lr;
      Obf[(size_t)(l * 4 + n) * 1024 + i * 16 + k] = f2bf(oacc[it][t] * izr[t]);
    }
}

// ---------------------------------------------------------------------------
// Wmap v3: zero LDS, zero barriers. Per (n, l-tile=64, s-tile=64): for each of
// 16 heads read Q-frag (2 b128) + K-frags (8 b128) from global (L2), MFMA,
// normalize with stored stats, accumulate Wmap[l][s][n]/H.
__global__ __launch_bounds__(256) void k_wmap(const unsigned short* __restrict__ Qbf,
    const unsigned short* __restrict__ Khbf, const float* __restrict__ stats,
    float* __restrict__ Wmap) {
  const int ob = blockIdx.x;
  const int b = (ob & 7) * 128 + (ob >> 3);
  const int st = b & 15, lt = (b >> 4) & 15, n = b >> 8;
  const int l0 = lt * 64, s0 = st * 64;
  const int tid = threadIdx.x, w = tid >> 6, lane = tid & 63;
  const int lr = lane & 15, lk = lane >> 4;

  f32x4 wsum[4];
#pragma unroll
  for (int i = 0; i < 4; ++i) wsum[i] = (f32x4){0.f, 0.f, 0.f, 0.f};

  for (int k = 0; k < 16; ++k) {
    const size_t hb = (size_t)(n * 16 + k) * 65536;
    // Q A-frag: row q = w*16+lr
    const unsigned short* qrow = Qbf + hb + (size_t)(l0 + w * 16 + lr) * 64;
    const bf16x8 a0 = *(const bf16x8*)(qrow + lk * 8);
    const bf16x8 a1 = *(const bf16x8*)(qrow + 32 + lk * 8);
    float mv[4], izv[4];
#pragma unroll
    for (int t = 0; t < 4; ++t) {
      const float2 mz = *(const float2*)(stats +
          ((size_t)(n * 16 + k) * 1024 + l0 + w * 16 + lk * 4 + t) * 2);
      mv[t] = mz.x; izv[t] = 1.f / mz.y;
    }
#pragma unroll
    for (int st2 = 0; st2 < 4; ++st2) {
      const unsigned short* kr = Khbf + hb + (size_t)(s0 + st2 * 16 + lr) * 64;
      const bf16x8 kb0 = *(const bf16x8*)(kr + lk * 8);
      const bf16x8 kb1 = *(const bf16x8*)(kr + 32 + lk * 8);
      f32x4 z = (f32x4){0.f, 0.f, 0.f, 0.f};
      z = __builtin_amdgcn_mfma_f32_16x16x32_bf16(a0, kb0, z, 0, 0, 0);
      z = __builtin_amdgcn_mfma_f32_16x16x32_bf16(a1, kb1, z, 0, 0, 0);
#pragma unroll
      for (int t = 0; t < 4; ++t)
        wsum[st2][t] += __expf(z[t] - mv[t]) * izv[t];
    }
  }
#pragma unroll
  for (int st2 = 0; st2 < 4; ++st2)
#pragma unroll
    for (int t = 0; t < 4; ++t) {
      const int l = l0 + w * 16 + lk * 4 + t;
      const int s = s0 + st2 * 16 + lr;
      Wmap[((size_t)l * 1024 + s) * 4 + n] = wsum[st2][t] * 0.0625f;
    }
}

// ---------------------------------------------------------------------------
extern "C" void kernel_launch(void* const* d_in, const int* in_sizes, int n_in,
                              void* d_out, int out_size, void* d_ws, size_t ws_size,
                              hipStream_t stream) {
  (void)in_sizes; (void)n_in; (void)out_size; (void)ws_size;
  const float* Q        = (const float*)d_in[0];
  const float* K        = (const float*)d_in[1];
  const float* V        = (const float*)d_in[2];
  const float* q_w      = (const float*)d_in[3];
  const float* k_w      = (const float*)d_in[4];
  const float* v_w      = (const float*)d_in[5];
  const float* out_w    = (const float*)d_in[6];
  const float* in_bias  = (const float*)d_in[7];
  const float* out_bias = (const float*)d_in[8];
  const float* attn_W   = (const float*)d_in[9];
  float* ws = (float*)d_ws;
  unsigned short* qw2bf = (unsigned short*)(ws + OFF_QW2BF);
  unsigned short* kwbf  = (unsigned short*)(ws + OFF_KWBF);
  unsigned short* vwbf  = (unsigned short*)(ws + OFF_VWBF);
  unsigned short* owtbf = (unsigned short*)(ws + OFF_OWTBF);
  float* qb2 = ws + OFF_QB2;
  unsigned short* Qwbf = (unsigned short*)(ws + OFF_QWBF);
  unsigned short* Khbf = (unsigned short*)(ws + OFF_KHBF);
  unsigned short* Vtbf = (unsigned short*)(ws + OFF_VTBF);
  float* st = ws + OFF_ST;
  unsigned short* Obf = (unsigned short*)(ws + OFF_OBF);
  float* out  = (float*)d_out;
  float* Wmap = out + 4194304;

  k_qw2<<<1024, 256, 0, stream>>>(q_w, attn_W, in_bias, qw2bf, qb2);
  k_cvt2<<<1024, 256, 0, stream>>>(k_w, v_w, kwbf, vwbf);
  k_tr<<<dim3(16, 16), 256, 0, stream>>>(out_w, owtbf);
  k_gemm<0><<<dim3(8, 32), 256, 0, stream>>>(Q, qw2bf, qb2, Qwbf);
  k_gemm<1><<<dim3(8, 32), 256, 0, stream>>>(K, kwbf, in_bias + 1024, Khbf);
  k_gemm<3><<<dim3(8, 32), 256, 0, stream>>>(V, vwbf, in_bias + 2048, Vtbf);
  k_flash<<<1024, 256, 0, stream>>>(Qwbf, Khbf, Vtbf, st, Obf);
  k_wmap<<<1024, 256, 0, stream>>>(Qwbf, Khbf, st, Wmap);
  k_gemm<2><<<dim3(8, 32), 256, 0, stream>>>(Obf, owtbf, out_bias, out);
}

// Round 5
// 272.473 us; speedup vs baseline: 1.4225x; 1.4225x over previous
//
#include <hip/hip_runtime.h>
#include <cstdint>

// Problem constants: L=S=1024, N=4, E=1024, H=16, D=64
typedef __bf16 bf16x8 __attribute__((ext_vector_type(8)));
typedef float f32x4 __attribute__((ext_vector_type(4)));

// ws layout (float-unit offsets):
static const size_t OFF_QW2BF = 0;         // [k*64+i][j] bf16 (1M ushort)
static const size_t OFF_KWBF  = 524288;    // [o][j] bf16
static const size_t OFF_VWBF  = 1048576;   // [o][j] bf16
static const size_t OFF_OWTBF = 1572864;   // [o][j] bf16 (out_w^T)
static const size_t OFF_QB2   = 2097152;   // 1024 f32
static const size_t OFF_QWBF  = 2098176;   // [n][k][l][i] bf16 (4M ushort)
static const size_t OFF_KHBF  = 4195328;   // [n][k][s][i] bf16
static const size_t OFF_VTBF  = 6292480;   // [n][k][i][s] bf16 (V^T per head)
static const size_t OFF_ST    = 8389632;   // [n][k][l][{m,Z}] f32 131072
static const size_t OFF_OBF   = 8520704;   // [l*4+n][e] bf16 (4M ushort)

__device__ inline unsigned short f2bf(float f) {
  union { float f; unsigned u; } v; v.f = f;
  const unsigned r = v.u + 0x7FFFu + ((v.u >> 16) & 1u);   // RNE
  return (unsigned short)(r >> 16);
}

// ---------------------------------------------------------------------------
// K0: fold attn_W into q_w (bf16 out): qw2[(k,i),j] = sum_o q_w[o*16+k,j]*attn_W[o,i,k]/32
__global__ __launch_bounds__(256) void k_qw2(const float* __restrict__ qw,
    const float* __restrict__ attnW, const float* __restrict__ bias0,
    unsigned short* __restrict__ qw2, float* __restrict__ qb2) {
  const int b = blockIdx.x;          // = k*64 + i
  const int k = b >> 6, i = b & 63;
  const int tid = threadIdx.x;
  __shared__ float aw[64];
  if (tid < 64) aw[tid] = attnW[(tid * 64 + i) * 16 + k] * 0.03125f; // fold 1/sqrt(E)
  __syncthreads();
  for (int j = tid; j < 1024; j += 256) {
    float acc = 0.f;
#pragma unroll 8
    for (int o = 0; o < 64; ++o) acc = fmaf(qw[(o * 16 + k) * 1024 + j], aw[o], acc);
    qw2[(size_t)b * 1024 + j] = f2bf(acc);
  }
  if (tid == 0) {
    float acc = 0.f;
    for (int o = 0; o < 64; ++o) acc = fmaf(bias0[o * 16 + k], aw[o], acc);
    qb2[b] = acc;
  }
}

// ---------------------------------------------------------------------------
// Convert k_w and v_w to bf16 (row layout preserved: [o][j])
__global__ __launch_bounds__(256) void k_cvt2(const float* __restrict__ a,
    const float* __restrict__ b, unsigned short* __restrict__ oa,
    unsigned short* __restrict__ ob) {
  const int i = blockIdx.x * 256 + threadIdx.x;
  const float4 va = ((const float4*)a)[i];
  ushort4 ha; ha.x = f2bf(va.x); ha.y = f2bf(va.y); ha.z = f2bf(va.z); ha.w = f2bf(va.w);
  ((ushort4*)oa)[i] = ha;
  const float4 vb = ((const float4*)b)[i];
  ushort4 hb; hb.x = f2bf(vb.x); hb.y = f2bf(vb.y); hb.z = f2bf(vb.z); hb.w = f2bf(vb.w);
  ((ushort4*)ob)[i] = hb;
}

// ---------------------------------------------------------------------------
// Transpose out_w [j][o] -> owT [o][j] bf16
__global__ __launch_bounds__(256) void k_tr(const float* __restrict__ w,
    unsigned short* __restrict__ wt) {
  __shared__ float t[64][65];
  const int j0 = blockIdx.y * 64, o0 = blockIdx.x * 64;
  const int tid = threadIdx.x;
  const int r = tid >> 4, c4 = tid & 15;
#pragma unroll
  for (int q = 0; q < 4; ++q) {
    const int row = r + q * 16;
    const float4 v = *(const float4*)&w[(size_t)(j0 + row) * 1024 + o0 + c4 * 4];
    t[row][c4 * 4 + 0] = v.x; t[row][c4 * 4 + 1] = v.y;
    t[row][c4 * 4 + 2] = v.z; t[row][c4 * 4 + 3] = v.w;
  }
  __syncthreads();
#pragma unroll
  for (int q = 0; q < 4; ++q) {
    const int orow = r + q * 16;
    ushort4 h;
    h.x = f2bf(t[c4 * 4 + 0][orow]); h.y = f2bf(t[c4 * 4 + 1][orow]);
    h.z = f2bf(t[c4 * 4 + 2][orow]); h.w = f2bf(t[c4 * 4 + 3][orow]);
    *(ushort4*)&wt[(size_t)(o0 + orow) * 1024 + j0 + c4 * 4] = h;
  }
}

// ---------------------------------------------------------------------------
// bf16 MFMA GEMM: C[m,o] = sum_j A[m,j]*B[o,j] + bias[o].  M=4096,O=1024,K=1024.
// MODE 0: A fp32 (Q), epilogue bf16 scatter -> Qw[n][k][l][i] (o = k*64+i)
// MODE 1: A fp32 (K), epilogue bf16 scatter -> Kh[n][k][s][i] (o = i*16+k)
// MODE 3: A fp32 (V), epilogue bf16 scatter -> Vt[n][k][i][s] (o = i*16+k)
// MODE 2: A bf16 (Obf), epilogue f32 direct C[m*1024+o]
template <int MODE>
__global__ __launch_bounds__(256) void k_gemm(const void* __restrict__ Ap,
    const unsigned short* __restrict__ Bbf, const float* __restrict__ bias,
    void* __restrict__ C) {
  __shared__ unsigned short As[128][40];
  __shared__ unsigned short Bs[128][40];
  const int tid = threadIdx.x;
  const int wid = tid >> 6, lane = tid & 63;
  const int wr = wid >> 1, wc = wid & 1;
  const int lr = lane & 15, lk = lane >> 4;
  const int m0 = blockIdx.y * 128, o0 = blockIdx.x * 128;
  f32x4 acc[4][4];
#pragma unroll
  for (int i = 0; i < 4; ++i)
#pragma unroll
    for (int j = 0; j < 4; ++j) acc[i][j] = (f32x4){0.f, 0.f, 0.f, 0.f};

  for (int k0 = 0; k0 < 1024; k0 += 32) {
    if (MODE == 2) {
      const unsigned short* A = (const unsigned short*)Ap;
#pragma unroll
      for (int q = 0; q < 2; ++q) {
        const int idx = tid + q * 256;
        const int row = idx >> 2, c8 = idx & 3;
        *(int4*)&As[row][c8 * 8] =
            *(const int4*)&A[(size_t)(m0 + row) * 1024 + k0 + c8 * 8];
      }
    } else {
      const float* A = (const float*)Ap;
#pragma unroll
      for (int q = 0; q < 4; ++q) {
        const int idx = tid + q * 256;
        const int row = idx >> 3, c4 = idx & 7;
        const float4 v = *(const float4*)&A[(size_t)(m0 + row) * 1024 + k0 + c4 * 4];
        ushort4 h; h.x = f2bf(v.x); h.y = f2bf(v.y); h.z = f2bf(v.z); h.w = f2bf(v.w);
        *(ushort4*)&As[row][c4 * 4] = h;
      }
    }
#pragma unroll
    for (int q = 0; q < 2; ++q) {
      const int idx = tid + q * 256;
      const int row = idx >> 2, c8 = idx & 3;
      *(int4*)&Bs[row][c8 * 8] =
          *(const int4*)&Bbf[(size_t)(o0 + row) * 1024 + k0 + c8 * 8];
    }
    __syncthreads();
    bf16x8 af[4], bfr[4];
#pragma unroll
    for (int f = 0; f < 4; ++f)
      af[f] = *(const bf16x8*)&As[wr * 64 + f * 16 + lr][lk * 8];
#pragma unroll
    for (int f = 0; f < 4; ++f)
      bfr[f] = *(const bf16x8*)&Bs[wc * 64 + f * 16 + lr][lk * 8];
#pragma unroll
    for (int i = 0; i < 4; ++i)
#pragma unroll
      for (int j = 0; j < 4; ++j)
        acc[i][j] = __builtin_amdgcn_mfma_f32_16x16x32_bf16(af[i], bfr[j], acc[i][j], 0, 0, 0);
    __syncthreads();
  }
#pragma unroll
  for (int fi = 0; fi < 4; ++fi)
#pragma unroll
    for (int fj = 0; fj < 4; ++fj) {
      const int o = o0 + wc * 64 + fj * 16 + lr;
      const float bo = bias[o];
#pragma unroll
      for (int t = 0; t < 4; ++t) {
        const int m = m0 + wr * 64 + fi * 16 + lk * 4 + t;
        const float v = acc[fi][fj][t] + bo;
        if (MODE == 0) {
          const int kk = o >> 6, ii = o & 63, l = m >> 2, nn = m & 3;
          ((unsigned short*)C)[(((size_t)(nn * 16 + kk) * 1024 + l) << 6) + ii] = f2bf(v);
        } else if (MODE == 1) {
          const int kk = o & 15, ii = o >> 4, s = m >> 2, nn = m & 3;
          ((unsigned short*)C)[(((size_t)(nn * 16 + kk) * 1024 + s) << 6) + ii] = f2bf(v);
        } else if (MODE == 3) {
          const int kk = o & 15, ii = o >> 4, s = m >> 2, nn = m & 3;
          ((unsigned short*)C)[(((size_t)(nn * 16 + kk) * 64 + ii) << 10) + s] = f2bf(v);
        } else {
          ((float*)C)[(size_t)m * 1024 + o] = v;
        }
      }
    }
}

// ---------------------------------------------------------------------------
// MFMA flash v5: per (n,k,l-tile=64); 4 waves x 16 q-rows.
// K [s][i] and Vt [i][s] staged in double-buffered LDS (pre-swizzled global
// source -> linear LDS write -> XOR-swizzled b128 frag reads, conflict-free;
// proven 0-conflict in R3). ONE barrier per tile. Swapped QK (A=K, B=Q):
// lane owns full score row for q=lane&15 -> in-register max/sum + 2 shfl_xor.
// P via wave-private swizzled LDS (4x b64 write, 2x b128 read). T14: next
// tile's global loads issued before compute.
__global__ __launch_bounds__(256) void k_flash(
    const unsigned short* __restrict__ Qbf, const unsigned short* __restrict__ Khbf,
    const unsigned short* __restrict__ Vtbf, float* __restrict__ stats,
    unsigned short* __restrict__ Obf) {
  __shared__ unsigned short Kd[2][64 * 64];
  __shared__ unsigned short Vd[2][64 * 64];
  __shared__ unsigned short Ps[4][16 * 64];
  const int ob = blockIdx.x;
  const int b = (ob & 7) * 128 + (ob >> 3);   // bijective XCD swizzle
  const int lt = b & 15, k = (b >> 4) & 15, n = b >> 8;
  const int l0 = lt * 64;
  const int tid = threadIdx.x, w = tid >> 6, lane = tid & 63;
  const int lr = lane & 15, lk = lane >> 4;
  const size_t hb = (size_t)(n * 16 + k) * 65536;
  // Q fragments (B-operand): row = lr, k-chunks lk*8 / 32+lk*8
  const unsigned short* qrow = Qbf + hb + (size_t)(l0 + w * 16 + lr) * 64;
  const bf16x8 qa0 = *(const bf16x8*)(qrow + lk * 8);
  const bf16x8 qa1 = *(const bf16x8*)(qrow + 32 + lk * 8);
  const int swz = lr & 7;
  // staging geometry: 16B chunk idx = q*256+tid -> linear LDS; source chunk
  // pre-swizzled c = pos ^ (row&7)
  int srow[2], scol[2];
#pragma unroll
  for (int q = 0; q < 2; ++q) {
    const int idx = q * 256 + tid;
    srow[q] = idx >> 3;
    scol[q] = (((idx & 7) ^ ((idx >> 3) & 7)) << 3);
  }
  const unsigned short* Kb = Khbf + hb;
  const unsigned short* Vb = Vtbf + hb;
  int4 kreg[2], vreg[2];
#pragma unroll
  for (int q = 0; q < 2; ++q) {
    kreg[q] = *(const int4*)(Kb + (size_t)srow[q] * 64 + scol[q]);
    vreg[q] = *(const int4*)(Vb + (size_t)srow[q] * 1024 + scol[q]);
  }
#pragma unroll
  for (int q = 0; q < 2; ++q) {
    *(int4*)&Kd[0][(q * 256 + tid) * 8] = kreg[q];
    *(int4*)&Vd[0][(q * 256 + tid) * 8] = vreg[q];
  }
  float m_ = -1e30f, Z_ = 0.f;            // per-lane: stats of q-row lr
  f32x4 oacc[4];
#pragma unroll
  for (int it = 0; it < 4; ++it) oacc[it] = (f32x4){0.f, 0.f, 0.f, 0.f};
  __syncthreads();

  for (int t0 = 0; t0 < 16; ++t0) {
    const int cur = t0 & 1;
    if (t0 < 15) {    // T14: issue next tile's global loads before compute
      const int s1 = (t0 + 1) * 64;
#pragma unroll
      for (int q = 0; q < 2; ++q) {
        kreg[q] = *(const int4*)(Kb + (size_t)(s1 + srow[q]) * 64 + scol[q]);
        vreg[q] = *(const int4*)(Vb + (size_t)srow[q] * 1024 + s1 + scol[q]);
      }
    }
    // swapped QK^T: lane holds S[q=lr][s = st*16 + lk*4 + t]
    f32x4 sc[4];
#pragma unroll
    for (int st = 0; st < 4; ++st) {
      const int r = st * 16 + lr;
      const bf16x8 kb0 = *(const bf16x8*)&Kd[cur][r * 64 + ((lk ^ (r & 7)) << 3)];
      const bf16x8 kb1 = *(const bf16x8*)&Kd[cur][r * 64 + (((4 + lk) ^ (r & 7)) << 3)];
      f32x4 z = (f32x4){0.f, 0.f, 0.f, 0.f};
      z = __builtin_amdgcn_mfma_f32_16x16x32_bf16(kb0, qa0, z, 0, 0, 0);
      sc[st] = __builtin_amdgcn_mfma_f32_16x16x32_bf16(kb1, qa1, z, 0, 0, 0);
    }
    // online softmax (reduce across lk groups: lanes lr+16*lk share q-row lr)
    float tm = fmaxf(fmaxf(fmaxf(sc[0][0], sc[0][1]), fmaxf(sc[0][2], sc[0][3])),
                     fmaxf(fmaxf(sc[1][0], sc[1][1]), fmaxf(sc[1][2], sc[1][3])));
    tm = fmaxf(tm, fmaxf(fmaxf(fmaxf(sc[2][0], sc[2][1]), fmaxf(sc[2][2], sc[2][3])),
                         fmaxf(fmaxf(sc[3][0], sc[3][1]), fmaxf(sc[3][2], sc[3][3]))));
    tm = fmaxf(tm, __shfl_xor(tm, 16));
    tm = fmaxf(tm, __shfl_xor(tm, 32));
    const float mn = fmaxf(m_, tm);
    const float fac = __expf(m_ - mn);
    m_ = mn;
    float rs = 0.f;
    float p[4][4];
#pragma unroll
    for (int st = 0; st < 4; ++st)
#pragma unroll
      for (int t = 0; t < 4; ++t) {
        p[st][t] = __expf(sc[st][t] - mn);
        rs += p[st][t];
      }
    rs += __shfl_xor(rs, 16);
    rs += __shfl_xor(rs, 32);
    Z_ = Z_ * fac + rs;
    // P write: 4 packed b64 (s = st*16+lk*4..+3), 8B-chunk XOR swizzle
#pragma unroll
    for (int st = 0; st < 4; ++st) {
      ushort4 pk;
      pk.x = f2bf(p[st][0]); pk.y = f2bf(p[st][1]);
      pk.z = f2bf(p[st][2]); pk.w = f2bf(p[st][3]);
      const int c = (st * 4 + lk) ^ (swz << 1);
      *(ushort4*)&Ps[w][lr * 64 + c * 4] = pk;
    }
    // redistribute fac to PV row layout (rows q = lk*4+t)
    float fr[4];
#pragma unroll
    for (int t = 0; t < 4; ++t) fr[t] = __shfl(fac, lk * 4 + t);
    const f32x4 facv = {fr[0], fr[1], fr[2], fr[3]};
    // P A-frags: row = lr, 16B chunk j' = j ^ swz
    const bf16x8 pa0 = *(const bf16x8*)&Ps[w][lr * 64 + ((lk ^ swz) << 3)];
    const bf16x8 pa1 = *(const bf16x8*)&Ps[w][lr * 64 + (((4 + lk) ^ swz) << 3)];
    // PV: C[col=q][row=i], V frags from LDS
#pragma unroll
    for (int it = 0; it < 4; ++it) {
      const int r = it * 16 + lr;
      const bf16x8 bv0 = *(const bf16x8*)&Vd[cur][r * 64 + ((lk ^ (r & 7)) << 3)];
      const bf16x8 bv1 = *(const bf16x8*)&Vd[cur][r * 64 + (((4 + lk) ^ (r & 7)) << 3)];
      f32x4 o = oacc[it] * facv;
      o = __builtin_amdgcn_mfma_f32_16x16x32_bf16(pa0, bv0, o, 0, 0, 0);
      oacc[it] = __builtin_amdgcn_mfma_f32_16x16x32_bf16(pa1, bv1, o, 0, 0, 0);
    }
    // stage next tile into the other buffer (no extra barrier needed)
    if (t0 < 15) {
#pragma unroll
      for (int q = 0; q < 2; ++q) {
        *(int4*)&Kd[cur ^ 1][(q * 256 + tid) * 8] = kreg[q];
        *(int4*)&Vd[cur ^ 1][(q * 256 + tid) * 8] = vreg[q];
      }
    }
    __syncthreads();
  }

  if (lane < 16) {
    const size_t so = ((size_t)(n * 16 + k) * 1024 + l0 + w * 16 + lr) * 2;
    stats[so] = m_;
    stats[so + 1] = Z_;
  }
  const float iz = 1.f / Z_;
  float izr[4];
#pragma unroll
  for (int t = 0; t < 4; ++t) izr[t] = __shfl(iz, lk * 4 + t);
#pragma unroll
  for (int it = 0; it < 4; ++it)
#pragma unroll
    for (int t = 0; t < 4; ++t) {
      const int l = l0 + w * 16 + lk * 4 + t;
      const int i = it * 16 + lr;
      Obf[(size_t)(l * 4 + n) * 1024 + i * 16 + k] = f2bf(oacc[it][t] * izr[t]);
    }
}

// ---------------------------------------------------------------------------
// Wmap v4: per (n, l-tile=64, s-tile=64); loop 16 heads. K tile double-buffered
// in LDS (amortized across 4 waves, 1 barrier/head, prefetch next head);
// Q-frags direct from global (each wave reads distinct rows - no reuse to
// exploit). Normalize with stored stats, accumulate Wmap[l][s][n]/H.
__global__ __launch_bounds__(256) void k_wmap(const unsigned short* __restrict__ Qbf,
    const unsigned short* __restrict__ Khbf, const float* __restrict__ stats,
    float* __restrict__ Wmap) {
  __shared__ unsigned short Kst[2][64 * 64];
  const int ob = blockIdx.x;
  const int b = (ob & 7) * 128 + (ob >> 3);
  const int st = b & 15, lt = (b >> 4) & 15, n = b >> 8;
  const int l0 = lt * 64, s0 = st * 64;
  const int tid = threadIdx.x, w = tid >> 6, lane = tid & 63;
  const int lr = lane & 15, lk = lane >> 4;
  int srow[2], scol[2];
#pragma unroll
  for (int q = 0; q < 2; ++q) {
    const int idx = q * 256 + tid;
    srow[q] = idx >> 3;
    scol[q] = (((idx & 7) ^ ((idx >> 3) & 7)) << 3);
  }
  int4 kreg[2];
#pragma unroll
  for (int q = 0; q < 2; ++q)
    kreg[q] = *(const int4*)(Khbf + (size_t)(n * 16) * 65536 +
                             (size_t)(s0 + srow[q]) * 64 + scol[q]);
#pragma unroll
  for (int q = 0; q < 2; ++q)
    *(int4*)&Kst[0][(q * 256 + tid) * 8] = kreg[q];
  f32x4 wsum[4];
#pragma unroll
  for (int i = 0; i < 4; ++i) wsum[i] = (f32x4){0.f, 0.f, 0.f, 0.f};
  __syncthreads();

  for (int k = 0; k < 16; ++k) {
    const int cur = k & 1;
    const size_t hb = (size_t)(n * 16 + k) * 65536;
    if (k < 15) {
      const size_t hb1 = (size_t)(n * 16 + k + 1) * 65536;
#pragma unroll
      for (int q = 0; q < 2; ++q)
        kreg[q] = *(const int4*)(Khbf + hb1 + (size_t)(s0 + srow[q]) * 64 + scol[q]);
    }
    // Q A-frag direct from global: row q = w*16+lr
    const unsigned short* qrow = Qbf + hb + (size_t)(l0 + w * 16 + lr) * 64;
    const bf16x8 a0 = *(const bf16x8*)(qrow + lk * 8);
    const bf16x8 a1 = *(const bf16x8*)(qrow + 32 + lk * 8);
    float mv[4], izv[4];
#pragma unroll
    for (int t = 0; t < 4; ++t) {
      const float2 mz = *(const float2*)(stats +
          ((size_t)(n * 16 + k) * 1024 + l0 + w * 16 + lk * 4 + t) * 2);
      mv[t] = mz.x; izv[t] = 1.f / mz.y;
    }
#pragma unroll
    for (int st2 = 0; st2 < 4; ++st2) {
      const int r = st2 * 16 + lr;
      const bf16x8 kb0 = *(const bf16x8*)&Kst[cur][r * 64 + ((lk ^ (r & 7)) << 3)];
      const bf16x8 kb1 = *(const bf16x8*)&Kst[cur][r * 64 + (((4 + lk) ^ (r & 7)) << 3)];
      f32x4 z = (f32x4){0.f, 0.f, 0.f, 0.f};
      z = __builtin_amdgcn_mfma_f32_16x16x32_bf16(a0, kb0, z, 0, 0, 0);
      z = __builtin_amdgcn_mfma_f32_16x16x32_bf16(a1, kb1, z, 0, 0, 0);
#pragma unroll
      for (int t = 0; t < 4; ++t)
        wsum[st2][t] += __expf(z[t] - mv[t]) * izv[t];
    }
    if (k < 15) {
#pragma unroll
      for (int q = 0; q < 2; ++q)
        *(int4*)&Kst[cur ^ 1][(q * 256 + tid) * 8] = kreg[q];
    }
    __syncthreads();
  }
#pragma unroll
  for (int st2 = 0; st2 < 4; ++st2)
#pragma unroll
    for (int t = 0; t < 4; ++t) {
      const int l = l0 + w * 16 + lk * 4 + t;
      const int s = s0 + st2 * 16 + lr;
      Wmap[((size_t)l * 1024 + s) * 4 + n] = wsum[st2][t] * 0.0625f;
    }
}

// ---------------------------------------------------------------------------
extern "C" void kernel_launch(void* const* d_in, const int* in_sizes, int n_in,
                              void* d_out, int out_size, void* d_ws, size_t ws_size,
                              hipStream_t stream) {
  (void)in_sizes; (void)n_in; (void)out_size; (void)ws_size;
  const float* Q        = (const float*)d_in[0];
  const float* K        = (const float*)d_in[1];
  const float* V        = (const float*)d_in[2];
  const float* q_w      = (const float*)d_in[3];
  const float* k_w      = (const float*)d_in[4];
  const float* v_w      = (const float*)d_in[5];
  const float* out_w    = (const float*)d_in[6];
  const float* in_bias  = (const float*)d_in[7];
  const float* out_bias = (const float*)d_in[8];
  const float* attn_W   = (const float*)d_in[9];
  float* ws = (float*)d_ws;
  unsigned short* qw2bf = (unsigned short*)(ws + OFF_QW2BF);
  unsigned short* kwbf  = (unsigned short*)(ws + OFF_KWBF);
  unsigned short* vwbf  = (unsigned short*)(ws + OFF_VWBF);
  unsigned short* owtbf = (unsigned short*)(ws + OFF_OWTBF);
  float* qb2 = ws + OFF_QB2;
  unsigned short* Qwbf = (unsigned short*)(ws + OFF_QWBF);
  unsigned short* Khbf = (unsigned short*)(ws + OFF_KHBF);
  unsigned short* Vtbf = (unsigned short*)(ws + OFF_VTBF);
  float* st = ws + OFF_ST;
  unsigned short* Obf = (unsigned short*)(ws + OFF_OBF);
  float* out  = (float*)d_out;
  float* Wmap = out + 4194304;

  k_qw2<<<1024, 256, 0, stream>>>(q_w, attn_W, in_bias, qw2bf, qb2);
  k_cvt2<<<1024, 256, 0, stream>>>(k_w, v_w, kwbf, vwbf);
  k_tr<<<dim3(16, 16), 256, 0, stream>>>(out_w, owtbf);
  k_gemm<0><<<dim3(8, 32), 256, 0, stream>>>(Q, qw2bf, qb2, Qwbf);
  k_gemm<1><<<dim3(8, 32), 256, 0, stream>>>(K, kwbf, in_bias + 1024, Khbf);
  k_gemm<3><<<dim3(8, 32), 256, 0, stream>>>(V, vwbf, in_bias + 2048, Vtbf);
  k_flash<<<1024, 256, 0, stream>>>(Qwbf, Khbf, Vtbf, st, Obf);
  k_wmap<<<1024, 256, 0, stream>>>(Qwbf, Khbf, st, Wmap);
  k_gemm<2><<<dim3(8, 32), 256, 0, stream>>>(Obf, owtbf, out_bias, out);
}

// Round 6
// 199.357 us; speedup vs baseline: 1.9442x; 1.3668x over previous
//
#include <hip/hip_runtime.h>
#include <cstdint>

// Problem constants: L=S=1024, N=4, E=1024, H=16, D=64
typedef __bf16 bf16x8 __attribute__((ext_vector_type(8)));
typedef float f32x4 __attribute__((ext_vector_type(4)));

// ws layout (float-unit offsets):
static const size_t OFF_QW2BF = 0;         // [k*64+i][j] bf16 (1M ushort)
static const size_t OFF_KWBF  = 524288;    // [o][j] bf16
static const size_t OFF_VWBF  = 1048576;   // [o][j] bf16
static const size_t OFF_OWTBF = 1572864;   // [o][j] bf16 (out_w^T)
static const size_t OFF_QB2   = 2097152;   // 1024 f32
static const size_t OFF_QWBF  = 2098176;   // [n][k][l][i] bf16 (4M ushort)
static const size_t OFF_KHBF  = 4195328;   // [n][k][s][i] bf16
static const size_t OFF_VTBF  = 6292480;   // [n][k][i][s] bf16 (V^T per head)
static const size_t OFF_ST    = 8389632;   // [n][k][l][{m,Z}] f32 131072
static const size_t OFF_OBF   = 8520704;   // [l*4+n][e] bf16 (4M ushort)

__device__ inline unsigned short f2bf(float f) {
  union { float f; unsigned u; } v; v.f = f;
  const unsigned r = v.u + 0x7FFFu + ((v.u >> 16) & 1u);   // RNE
  return (unsigned short)(r >> 16);
}

// ---------------------------------------------------------------------------
// K0: fold attn_W into q_w (bf16 out): qw2[(k,i),j] = sum_o q_w[o*16+k,j]*attn_W[o,i,k]/32
__global__ __launch_bounds__(256) void k_qw2(const float* __restrict__ qw,
    const float* __restrict__ attnW, const float* __restrict__ bias0,
    unsigned short* __restrict__ qw2, float* __restrict__ qb2) {
  const int b = blockIdx.x;          // = k*64 + i
  const int k = b >> 6, i = b & 63;
  const int tid = threadIdx.x;
  __shared__ float aw[64];
  if (tid < 64) aw[tid] = attnW[(tid * 64 + i) * 16 + k] * 0.03125f; // fold 1/sqrt(E)
  __syncthreads();
  for (int j = tid; j < 1024; j += 256) {
    float acc = 0.f;
#pragma unroll 8
    for (int o = 0; o < 64; ++o) acc = fmaf(qw[(o * 16 + k) * 1024 + j], aw[o], acc);
    qw2[(size_t)b * 1024 + j] = f2bf(acc);
  }
  if (tid == 0) {
    float acc = 0.f;
    for (int o = 0; o < 64; ++o) acc = fmaf(bias0[o * 16 + k], aw[o], acc);
    qb2[b] = acc;
  }
}

// ---------------------------------------------------------------------------
// Convert k_w and v_w to bf16 (row layout preserved: [o][j])
__global__ __launch_bounds__(256) void k_cvt2(const float* __restrict__ a,
    const float* __restrict__ b, unsigned short* __restrict__ oa,
    unsigned short* __restrict__ ob) {
  const int i = blockIdx.x * 256 + threadIdx.x;
  const float4 va = ((const float4*)a)[i];
  ushort4 ha; ha.x = f2bf(va.x); ha.y = f2bf(va.y); ha.z = f2bf(va.z); ha.w = f2bf(va.w);
  ((ushort4*)oa)[i] = ha;
  const float4 vb = ((const float4*)b)[i];
  ushort4 hb; hb.x = f2bf(vb.x); hb.y = f2bf(vb.y); hb.z = f2bf(vb.z); hb.w = f2bf(vb.w);
  ((ushort4*)ob)[i] = hb;
}

// ---------------------------------------------------------------------------
// Transpose out_w [j][o] -> owT [o][j] bf16
__global__ __launch_bounds__(256) void k_tr(const float* __restrict__ w,
    unsigned short* __restrict__ wt) {
  __shared__ float t[64][65];
  const int j0 = blockIdx.y * 64, o0 = blockIdx.x * 64;
  const int tid = threadIdx.x;
  const int r = tid >> 4, c4 = tid & 15;
#pragma unroll
  for (int q = 0; q < 4; ++q) {
    const int row = r + q * 16;
    const float4 v = *(const float4*)&w[(size_t)(j0 + row) * 1024 + o0 + c4 * 4];
    t[row][c4 * 4 + 0] = v.x; t[row][c4 * 4 + 1] = v.y;
    t[row][c4 * 4 + 2] = v.z; t[row][c4 * 4 + 3] = v.w;
  }
  __syncthreads();
#pragma unroll
  for (int q = 0; q < 4; ++q) {
    const int orow = r + q * 16;
    ushort4 h;
    h.x = f2bf(t[c4 * 4 + 0][orow]); h.y = f2bf(t[c4 * 4 + 1][orow]);
    h.z = f2bf(t[c4 * 4 + 2][orow]); h.w = f2bf(t[c4 * 4 + 3][orow]);
    *(ushort4*)&wt[(size_t)(o0 + orow) * 1024 + j0 + c4 * 4] = h;
  }
}

// ---------------------------------------------------------------------------
// Merged in-projection GEMMs (Q,K,V in one launch for 3 blocks/CU occupancy).
// C[m,o] = sum_j A[m,j]*B[o,j] + bias[o]; M=4096, O=1024, K=1024 each.
// 128x128 tile, BK=32, 4 waves (2x2 of 64x64), mfma 16x16x32.
// id swizzle: blocks sharing an A-panel (all 8 o-blocks of one (by,bz)) get
// ids {x, x+8, ..., x+56} -> same XCD under id%8 round-robin => A-panel
// fetched into ONE L2 instead of 8.
// bz=0: A=Q,B=qw2 -> Qw[n][k][l][i] (o=k*64+i); bz=1: A=K -> Kh[n][k][s][i]
// (o=i*16+k); bz=2: A=V -> Vt[n][k][i][s] (o=i*16+k).
__global__ __launch_bounds__(256) void k_gemm_in(
    const float* __restrict__ Qf, const float* __restrict__ Kf,
    const float* __restrict__ Vf, const unsigned short* __restrict__ Bq,
    const unsigned short* __restrict__ Bk, const unsigned short* __restrict__ Bv,
    const float* __restrict__ bq, const float* __restrict__ bk,
    const float* __restrict__ bv, unsigned short* __restrict__ Cq,
    unsigned short* __restrict__ Ck, unsigned short* __restrict__ Cv) {
  __shared__ unsigned short As[128][40];
  __shared__ unsigned short Bs[128][40];
  const int id = blockIdx.x;                     // 0..767
  const int g  = (id & 7) + ((id >> 6) << 3);    // 0..95 (A-panel group)
  const int bx = (id >> 3) & 7;                  // o-block
  const int by = g & 31, bz = g >> 5;            // m-block, which gemm
  const float* A          = bz == 0 ? Qf : (bz == 1 ? Kf : Vf);
  const unsigned short* B = bz == 0 ? Bq : (bz == 1 ? Bk : Bv);
  const float* bias       = bz == 0 ? bq : (bz == 1 ? bk : bv);
  unsigned short* C       = bz == 0 ? Cq : (bz == 1 ? Ck : Cv);
  const int m0 = by * 128, o0 = bx * 128;
  const int tid = threadIdx.x;
  const int wid = tid >> 6, lane = tid & 63;
  const int wr = wid >> 1, wc = wid & 1;
  const int lr = lane & 15, lk = lane >> 4;
  f32x4 acc[4][4];
#pragma unroll
  for (int i = 0; i < 4; ++i)
#pragma unroll
    for (int j = 0; j < 4; ++j) acc[i][j] = (f32x4){0.f, 0.f, 0.f, 0.f};

  for (int k0 = 0; k0 < 1024; k0 += 32) {
#pragma unroll
    for (int q = 0; q < 4; ++q) {
      const int idx = tid + q * 256;
      const int row = idx >> 3, c4 = idx & 7;
      const float4 v = *(const float4*)&A[(size_t)(m0 + row) * 1024 + k0 + c4 * 4];
      ushort4 h; h.x = f2bf(v.x); h.y = f2bf(v.y); h.z = f2bf(v.z); h.w = f2bf(v.w);
      *(ushort4*)&As[row][c4 * 4] = h;
    }
#pragma unroll
    for (int q = 0; q < 2; ++q) {
      const int idx = tid + q * 256;
      const int row = idx >> 2, c8 = idx & 3;
      *(int4*)&Bs[row][c8 * 8] =
          *(const int4*)&B[(size_t)(o0 + row) * 1024 + k0 + c8 * 8];
    }
    __syncthreads();
    bf16x8 af[4], bfr[4];
#pragma unroll
    for (int f = 0; f < 4; ++f)
      af[f] = *(const bf16x8*)&As[wr * 64 + f * 16 + lr][lk * 8];
#pragma unroll
    for (int f = 0; f < 4; ++f)
      bfr[f] = *(const bf16x8*)&Bs[wc * 64 + f * 16 + lr][lk * 8];
#pragma unroll
    for (int i = 0; i < 4; ++i)
#pragma unroll
      for (int j = 0; j < 4; ++j)
        acc[i][j] = __builtin_amdgcn_mfma_f32_16x16x32_bf16(af[i], bfr[j], acc[i][j], 0, 0, 0);
    __syncthreads();
  }
#pragma unroll
  for (int fi = 0; fi < 4; ++fi)
#pragma unroll
    for (int fj = 0; fj < 4; ++fj) {
      const int o = o0 + wc * 64 + fj * 16 + lr;
      const float bo = bias[o];
#pragma unroll
      for (int t = 0; t < 4; ++t) {
        const int m = m0 + wr * 64 + fi * 16 + lk * 4 + t;
        const float v = acc[fi][fj][t] + bo;
        const int l = m >> 2, nn = m & 3;
        if (bz == 0) {
          const int kk = o >> 6, ii = o & 63;
          C[(((size_t)(nn * 16 + kk) * 1024 + l) << 6) + ii] = f2bf(v);
        } else if (bz == 1) {
          const int kk = o & 15, ii = o >> 4;
          C[(((size_t)(nn * 16 + kk) * 1024 + l) << 6) + ii] = f2bf(v);
        } else {
          const int kk = o & 15, ii = o >> 4;
          C[(((size_t)(nn * 16 + kk) * 64 + ii) << 10) + l] = f2bf(v);
        }
      }
    }
}

// ---------------------------------------------------------------------------
// Out-projection GEMM: C[m,o] = sum_j Obf[m,j]*owT[o,j] + bias[o], f32 out.
// 64x128 tile (512 blocks -> 2 blocks/CU), BK=32, 4 waves (2x2 of 32x64).
// Same XCD-chunked id swizzle (g = A-panel group of 8 o-blocks).
__global__ __launch_bounds__(256) void k_gemm_out(
    const unsigned short* __restrict__ A, const unsigned short* __restrict__ B,
    const float* __restrict__ bias, float* __restrict__ C) {
  __shared__ unsigned short As[64][40];
  __shared__ unsigned short Bs[128][40];
  const int id = blockIdx.x;                     // 0..511
  const int g  = (id & 7) + ((id >> 6) << 3);    // 0..63 m-block
  const int bx = (id >> 3) & 7;                  // o-block
  const int m0 = g * 64, o0 = bx * 128;
  const int tid = threadIdx.x;
  const int wid = tid >> 6, lane = tid & 63;
  const int wr = wid >> 1, wc = wid & 1;
  const int lr = lane & 15, lk = lane >> 4;
  f32x4 acc[2][4];
#pragma unroll
  for (int i = 0; i < 2; ++i)
#pragma unroll
    for (int j = 0; j < 4; ++j) acc[i][j] = (f32x4){0.f, 0.f, 0.f, 0.f};

  for (int k0 = 0; k0 < 1024; k0 += 32) {
    {
      const int row = tid >> 2, c8 = tid & 3;
      *(int4*)&As[row][c8 * 8] =
          *(const int4*)&A[(size_t)(m0 + row) * 1024 + k0 + c8 * 8];
    }
#pragma unroll
    for (int q = 0; q < 2; ++q) {
      const int idx = tid + q * 256;
      const int row = idx >> 2, c8 = idx & 3;
      *(int4*)&Bs[row][c8 * 8] =
          *(const int4*)&B[(size_t)(o0 + row) * 1024 + k0 + c8 * 8];
    }
    __syncthreads();
    bf16x8 af[2], bfr[4];
#pragma unroll
    for (int f = 0; f < 2; ++f)
      af[f] = *(const bf16x8*)&As[wr * 32 + f * 16 + lr][lk * 8];
#pragma unroll
    for (int f = 0; f < 4; ++f)
      bfr[f] = *(const bf16x8*)&Bs[wc * 64 + f * 16 + lr][lk * 8];
#pragma unroll
    for (int i = 0; i < 2; ++i)
#pragma unroll
      for (int j = 0; j < 4; ++j)
        acc[i][j] = __builtin_amdgcn_mfma_f32_16x16x32_bf16(af[i], bfr[j], acc[i][j], 0, 0, 0);
    __syncthreads();
  }
#pragma unroll
  for (int fi = 0; fi < 2; ++fi)
#pragma unroll
    for (int fj = 0; fj < 4; ++fj) {
      const int o = o0 + wc * 64 + fj * 16 + lr;
      const float bo = bias[o];
#pragma unroll
      for (int t = 0; t < 4; ++t) {
        const int m = m0 + wr * 32 + fi * 16 + lk * 4 + t;
        C[(size_t)m * 1024 + o] = acc[fi][fj][t] + bo;
      }
    }
}

// ---------------------------------------------------------------------------
// MFMA flash v5: per (n,k,l-tile=64); 4 waves x 16 q-rows.
// K [s][i] and Vt [i][s] staged in double-buffered LDS (pre-swizzled global
// source -> linear LDS write -> XOR-swizzled b128 frag reads, conflict-free).
// ONE barrier per tile. Swapped QK (A=K, B=Q): lane owns full score row for
// q=lane&15 -> in-register max/sum + 2 shfl_xor. P via wave-private swizzled
// LDS. T14: next tile's global loads issued before compute.
__global__ __launch_bounds__(256) void k_flash(
    const unsigned short* __restrict__ Qbf, const unsigned short* __restrict__ Khbf,
    const unsigned short* __restrict__ Vtbf, float* __restrict__ stats,
    unsigned short* __restrict__ Obf) {
  __shared__ unsigned short Kd[2][64 * 64];
  __shared__ unsigned short Vd[2][64 * 64];
  __shared__ unsigned short Ps[4][16 * 64];
  const int ob = blockIdx.x;
  const int b = (ob & 7) * 128 + (ob >> 3);   // bijective XCD swizzle
  const int lt = b & 15, k = (b >> 4) & 15, n = b >> 8;
  const int l0 = lt * 64;
  const int tid = threadIdx.x, w = tid >> 6, lane = tid & 63;
  const int lr = lane & 15, lk = lane >> 4;
  const size_t hb = (size_t)(n * 16 + k) * 65536;
  const unsigned short* qrow = Qbf + hb + (size_t)(l0 + w * 16 + lr) * 64;
  const bf16x8 qa0 = *(const bf16x8*)(qrow + lk * 8);
  const bf16x8 qa1 = *(const bf16x8*)(qrow + 32 + lk * 8);
  const int swz = lr & 7;
  int srow[2], scol[2];
#pragma unroll
  for (int q = 0; q < 2; ++q) {
    const int idx = q * 256 + tid;
    srow[q] = idx >> 3;
    scol[q] = (((idx & 7) ^ ((idx >> 3) & 7)) << 3);
  }
  const unsigned short* Kb = Khbf + hb;
  const unsigned short* Vb = Vtbf + hb;
  int4 kreg[2], vreg[2];
#pragma unroll
  for (int q = 0; q < 2; ++q) {
    kreg[q] = *(const int4*)(Kb + (size_t)srow[q] * 64 + scol[q]);
    vreg[q] = *(const int4*)(Vb + (size_t)srow[q] * 1024 + scol[q]);
  }
#pragma unroll
  for (int q = 0; q < 2; ++q) {
    *(int4*)&Kd[0][(q * 256 + tid) * 8] = kreg[q];
    *(int4*)&Vd[0][(q * 256 + tid) * 8] = vreg[q];
  }
  float m_ = -1e30f, Z_ = 0.f;
  f32x4 oacc[4];
#pragma unroll
  for (int it = 0; it < 4; ++it) oacc[it] = (f32x4){0.f, 0.f, 0.f, 0.f};
  __syncthreads();

  for (int t0 = 0; t0 < 16; ++t0) {
    const int cur = t0 & 1;
    if (t0 < 15) {
      const int s1 = (t0 + 1) * 64;
#pragma unroll
      for (int q = 0; q < 2; ++q) {
        kreg[q] = *(const int4*)(Kb + (size_t)(s1 + srow[q]) * 64 + scol[q]);
        vreg[q] = *(const int4*)(Vb + (size_t)srow[q] * 1024 + s1 + scol[q]);
      }
    }
    f32x4 sc[4];
#pragma unroll
    for (int st = 0; st < 4; ++st) {
      const int r = st * 16 + lr;
      const bf16x8 kb0 = *(const bf16x8*)&Kd[cur][r * 64 + ((lk ^ (r & 7)) << 3)];
      const bf16x8 kb1 = *(const bf16x8*)&Kd[cur][r * 64 + (((4 + lk) ^ (r & 7)) << 3)];
      f32x4 z = (f32x4){0.f, 0.f, 0.f, 0.f};
      z = __builtin_amdgcn_mfma_f32_16x16x32_bf16(kb0, qa0, z, 0, 0, 0);
      sc[st] = __builtin_amdgcn_mfma_f32_16x16x32_bf16(kb1, qa1, z, 0, 0, 0);
    }
    float tm = fmaxf(fmaxf(fmaxf(sc[0][0], sc[0][1]), fmaxf(sc[0][2], sc[0][3])),
                     fmaxf(fmaxf(sc[1][0], sc[1][1]), fmaxf(sc[1][2], sc[1][3])));
    tm = fmaxf(tm, fmaxf(fmaxf(fmaxf(sc[2][0], sc[2][1]), fmaxf(sc[2][2], sc[2][3])),
                         fmaxf(fmaxf(sc[3][0], sc[3][1]), fmaxf(sc[3][2], sc[3][3]))));
    tm = fmaxf(tm, __shfl_xor(tm, 16));
    tm = fmaxf(tm, __shfl_xor(tm, 32));
    const float mn = fmaxf(m_, tm);
    const float fac = __expf(m_ - mn);
    m_ = mn;
    float rs = 0.f;
    float p[4][4];
#pragma unroll
    for (int st = 0; st < 4; ++st)
#pragma unroll
      for (int t = 0; t < 4; ++t) {
        p[st][t] = __expf(sc[st][t] - mn);
        rs += p[st][t];
      }
    rs += __shfl_xor(rs, 16);
    rs += __shfl_xor(rs, 32);
    Z_ = Z_ * fac + rs;
#pragma unroll
    for (int st = 0; st < 4; ++st) {
      ushort4 pk;
      pk.x = f2bf(p[st][0]); pk.y = f2bf(p[st][1]);
      pk.z = f2bf(p[st][2]); pk.w = f2bf(p[st][3]);
      const int c = (st * 4 + lk) ^ (swz << 1);
      *(ushort4*)&Ps[w][lr * 64 + c * 4] = pk;
    }
    float fr[4];
#pragma unroll
    for (int t = 0; t < 4; ++t) fr[t] = __shfl(fac, lk * 4 + t);
    const f32x4 facv = {fr[0], fr[1], fr[2], fr[3]};
    const bf16x8 pa0 = *(const bf16x8*)&Ps[w][lr * 64 + ((lk ^ swz) << 3)];
    const bf16x8 pa1 = *(const bf16x8*)&Ps[w][lr * 64 + (((4 + lk) ^ swz) << 3)];
#pragma unroll
    for (int it = 0; it < 4; ++it) {
      const int r = it * 16 + lr;
      const bf16x8 bv0 = *(const bf16x8*)&Vd[cur][r * 64 + ((lk ^ (r & 7)) << 3)];
      const bf16x8 bv1 = *(const bf16x8*)&Vd[cur][r * 64 + (((4 + lk) ^ (r & 7)) << 3)];
      f32x4 o = oacc[it] * facv;
      o = __builtin_amdgcn_mfma_f32_16x16x32_bf16(pa0, bv0, o, 0, 0, 0);
      oacc[it] = __builtin_amdgcn_mfma_f32_16x16x32_bf16(pa1, bv1, o, 0, 0, 0);
    }
    if (t0 < 15) {
#pragma unroll
      for (int q = 0; q < 2; ++q) {
        *(int4*)&Kd[cur ^ 1][(q * 256 + tid) * 8] = kreg[q];
        *(int4*)&Vd[cur ^ 1][(q * 256 + tid) * 8] = vreg[q];
      }
    }
    __syncthreads();
  }

  if (lane < 16) {
    const size_t so = ((size_t)(n * 16 + k) * 1024 + l0 + w * 16 + lr) * 2;
    stats[so] = m_;
    stats[so + 1] = Z_;
  }
  const float iz = 1.f / Z_;
  float izr[4];
#pragma unroll
  for (int t = 0; t < 4; ++t) izr[t] = __shfl(iz, lk * 4 + t);
#pragma unroll
  for (int it = 0; it < 4; ++it)
#pragma unroll
    for (int t = 0; t < 4; ++t) {
      const int l = l0 + w * 16 + lk * 4 + t;
      const int i = it * 16 + lr;
      Obf[(size_t)(l * 4 + n) * 1024 + i * 16 + k] = f2bf(oacc[it][t] * izr[t]);
    }
}

// ---------------------------------------------------------------------------
// Wmap v4: per (n, l-tile=64, s-tile=64); loop 16 heads. K tile double-buffered
// in LDS (amortized across 4 waves, 1 barrier/head, prefetch next head);
// Q-frags direct from global. Normalize with stored stats -> Wmap[l][s][n]/H.
__global__ __launch_bounds__(256) void k_wmap(const unsigned short* __restrict__ Qbf,
    const unsigned short* __restrict__ Khbf, const float* __restrict__ stats,
    float* __restrict__ Wmap) {
  __shared__ unsigned short Kst[2][64 * 64];
  const int ob = blockIdx.x;
  const int b = (ob & 7) * 128 + (ob >> 3);
  const int st = b & 15, lt = (b >> 4) & 15, n = b >> 8;
  const int l0 = lt * 64, s0 = st * 64;
  const int tid = threadIdx.x, w = tid >> 6, lane = tid & 63;
  const int lr = lane & 15, lk = lane >> 4;
  int srow[2], scol[2];
#pragma unroll
  for (int q = 0; q < 2; ++q) {
    const int idx = q * 256 + tid;
    srow[q] = idx >> 3;
    scol[q] = (((idx & 7) ^ ((idx >> 3) & 7)) << 3);
  }
  int4 kreg[2];
#pragma unroll
  for (int q = 0; q < 2; ++q)
    kreg[q] = *(const int4*)(Khbf + (size_t)(n * 16) * 65536 +
                             (size_t)(s0 + srow[q]) * 64 + scol[q]);
#pragma unroll
  for (int q = 0; q < 2; ++q)
    *(int4*)&Kst[0][(q * 256 + tid) * 8] = kreg[q];
  f32x4 wsum[4];
#pragma unroll
  for (int i = 0; i < 4; ++i) wsum[i] = (f32x4){0.f, 0.f, 0.f, 0.f};
  __syncthreads();

  for (int k = 0; k < 16; ++k) {
    const int cur = k & 1;
    const size_t hb = (size_t)(n * 16 + k) * 65536;
    if (k < 15) {
      const size_t hb1 = (size_t)(n * 16 + k + 1) * 65536;
#pragma unroll
      for (int q = 0; q < 2; ++q)
        kreg[q] = *(const int4*)(Khbf + hb1 + (size_t)(s0 + srow[q]) * 64 + scol[q]);
    }
    const unsigned short* qrow = Qbf + hb + (size_t)(l0 + w * 16 + lr) * 64;
    const bf16x8 a0 = *(const bf16x8*)(qrow + lk * 8);
    const bf16x8 a1 = *(const bf16x8*)(qrow + 32 + lk * 8);
    float mv[4], izv[4];
#pragma unroll
    for (int t = 0; t < 4; ++t) {
      const float2 mz = *(const float2*)(stats +
          ((size_t)(n * 16 + k) * 1024 + l0 + w * 16 + lk * 4 + t) * 2);
      mv[t] = mz.x; izv[t] = 1.f / mz.y;
    }
#pragma unroll
    for (int st2 = 0; st2 < 4; ++st2) {
      const int r = st2 * 16 + lr;
      const bf16x8 kb0 = *(const bf16x8*)&Kst[cur][r * 64 + ((lk ^ (r & 7)) << 3)];
      const bf16x8 kb1 = *(const bf16x8*)&Kst[cur][r * 64 + (((4 + lk) ^ (r & 7)) << 3)];
      f32x4 z = (f32x4){0.f, 0.f, 0.f, 0.f};
      z = __builtin_amdgcn_mfma_f32_16x16x32_bf16(a0, kb0, z, 0, 0, 0);
      z = __builtin_amdgcn_mfma_f32_16x16x32_bf16(a1, kb1, z, 0, 0, 0);
#pragma unroll
      for (int t = 0; t < 4; ++t)
        wsum[st2][t] += __expf(z[t] - mv[t]) * izv[t];
    }
    if (k < 15) {
#pragma unroll
      for (int q = 0; q < 2; ++q)
        *(int4*)&Kst[cur ^ 1][(q * 256 + tid) * 8] = kreg[q];
    }
    __syncthreads();
  }
#pragma unroll
  for (int st2 = 0; st2 < 4; ++st2)
#pragma unroll
    for (int t = 0; t < 4; ++t) {
      const int l = l0 + w * 16 + lk * 4 + t;
      const int s = s0 + st2 * 16 + lr;
      Wmap[((size_t)l * 1024 + s) * 4 + n] = wsum[st2][t] * 0.0625f;
    }
}

// ---------------------------------------------------------------------------
extern "C" void kernel_launch(void* const* d_in, const int* in_sizes, int n_in,
                              void* d_out, int out_size, void* d_ws, size_t ws_size,
                              hipStream_t stream) {
  (void)in_sizes; (void)n_in; (void)out_size; (void)ws_size;
  const float* Q        = (const float*)d_in[0];
  const float* K        = (const float*)d_in[1];
  const float* V        = (const float*)d_in[2];
  const float* q_w      = (const float*)d_in[3];
  const float* k_w      = (const float*)d_in[4];
  const float* v_w      = (const float*)d_in[5];
  const float* out_w    = (const float*)d_in[6];
  const float* in_bias  = (const float*)d_in[7];
  const float* out_bias = (const float*)d_in[8];
  const float* attn_W   = (const float*)d_in[9];
  float* ws = (float*)d_ws;
  unsigned short* qw2bf = (unsigned short*)(ws + OFF_QW2BF);
  unsigned short* kwbf  = (unsigned short*)(ws + OFF_KWBF);
  unsigned short* vwbf  = (unsigned short*)(ws + OFF_VWBF);
  unsigned short* owtbf = (unsigned short*)(ws + OFF_OWTBF);
  float* qb2 = ws + OFF_QB2;
  unsigned short* Qwbf = (unsigned short*)(ws + OFF_QWBF);
  unsigned short* Khbf = (unsigned short*)(ws + OFF_KHBF);
  unsigned short* Vtbf = (unsigned short*)(ws + OFF_VTBF);
  float* st = ws + OFF_ST;
  unsigned short* Obf = (unsigned short*)(ws + OFF_OBF);
  float* out  = (float*)d_out;
  float* Wmap = out + 4194304;

  k_qw2<<<1024, 256, 0, stream>>>(q_w, attn_W, in_bias, qw2bf, qb2);
  k_cvt2<<<1024, 256, 0, stream>>>(k_w, v_w, kwbf, vwbf);
  k_tr<<<dim3(16, 16), 256, 0, stream>>>(out_w, owtbf);
  k_gemm_in<<<768, 256, 0, stream>>>(Q, K, V, qw2bf, kwbf, vwbf,
                                     qb2, in_bias + 1024, in_bias + 2048,
                                     Qwbf, Khbf, Vtbf);
  k_flash<<<1024, 256, 0, stream>>>(Qwbf, Khbf, Vtbf, st, Obf);
  k_wmap<<<1024, 256, 0, stream>>>(Qwbf, Khbf, st, Wmap);
  k_gemm_out<<<512, 256, 0, stream>>>(Obf, owtbf, out_bias, out);
}